// Round 21
// baseline (330.074 us; speedup 1.0000x reference)
//
#include <hip/hip_runtime.h>
#include <hip/hip_bf16.h>

typedef __bf16 bf16;
typedef __bf16 bf16x4 __attribute__((ext_vector_type(4)));
typedef __bf16 bf16x8 __attribute__((ext_vector_type(8)));
typedef float f32x4 __attribute__((ext_vector_type(4)));

#define NB   32768
#define EMB  768
#define MSUB 32
#define KC   256
#define DSUB 24

// ws layout (bytes):
//   [0,     512K )  cb_pad: bf16 [32][256][32]  (d padded 24->32 with zeros)
//   [1M,  2.125M)  rot_f : bf16 fragment-contiguous rotation (see R14)

__device__ __forceinline__ bf16x8 cvt8(float4 a, float4 b) {
    bf16x8 r;
    r[0] = (bf16)a.x; r[1] = (bf16)a.y; r[2] = (bf16)a.z; r[3] = (bf16)a.w;
    r[4] = (bf16)b.x; r[5] = (bf16)b.y; r[6] = (bf16)b.z; r[7] = (bf16)b.w;
    return r;
}

// LDS-only barrier: waits LDS ops (lgkmcnt) but NOT global stores (vmcnt).
__device__ __forceinline__ void lds_barrier() {
    asm volatile("s_waitcnt lgkmcnt(0)" ::: "memory");
    __builtin_amdgcn_s_barrier();
    __builtin_amdgcn_sched_barrier(0);
}

// ---------------------------------------------------------------- kernel 0
__global__ __launch_bounds__(256, 4)
void pq_prep(const float* __restrict__ cb, const float* __restrict__ rot,
             bf16* __restrict__ cb_pad, bf16* __restrict__ rot_f) {
    const int b = blockIdx.x;
    const int t = threadIdx.x;
    if (b < 288) {                       // rot -> fragment-contiguous rot_f
        const int o     = b * 2048 + t * 8;
        const int chunk = o >> 9;              // (jt*24 + et)
        const int lane8 = o & 511;
        const int l15   = (lane8 >> 3) & 15;
        const int lg    = lane8 >> 7;
        const int jj    = (chunk / 24) * 16 + l15;
        const int ee    = (chunk % 24) * 32 + lg * 8;
        const float* rp = rot + (size_t)jj * EMB + ee;
        *(bf16x8*)(rot_f + o) = cvt8(*(const float4*)rp, *(const float4*)(rp + 4));
    } else {                             // cb pad+cvt: [m][k][24] -> bf16 [m][k][32]
        const int o  = (b - 288) * 2048 + t * 8;
        const int m  = o >> 13;
        const int k  = (o >> 5) & 255;
        const int d0 = o & 31;
        bf16x8 v;
        if (d0 < DSUB) {
            const float* cp = cb + (size_t)(m * KC + k) * DSUB + d0;
            v = cvt8(*(const float4*)cp, *(const float4*)(cp + 4));
        } else {
            const float4 fz = {0.f, 0.f, 0.f, 0.f};
            v = cvt8(fz, fz);
        }
        *(bf16x8*)(cb_pad + o) = v;
    }
}

// ---------------------------------------------------------------- kernel 1
// FUSED rot + scores, v5: persistent 2-tile blocks (grid 512) + register
// prefetch of x(tile1) during B(tile0). A(tile1)'s HBM latency is hidden
// under ~100us of B(tile0) stores; its exposed cost is MFMA+epilogue only.
// Phase B = R16's proven lean body (one m/phase, XOR slab, lgkm barriers,
// full 1KB line drains). VGPR budget: pf[12] f32x4 (48) + B live (~45) +
// misc < 128 -> 2 blocks/CU preserved.
__global__ __launch_bounds__(512, 4)
void pq_fused5(const float* __restrict__ x, const bf16* __restrict__ rot_f,
               const bf16* __restrict__ cb_pad, float* __restrict__ out) {
    __shared__ __align__(16) char smem[81920];
    bf16*  xl  = (bf16*)smem;                  // 49152 B: x granules, then xr
    float* stg = (float*)(smem + 49152);       // 32768 B: one m-slice slab

    const int tid  = threadIdx.x;
    const int w    = tid >> 6;          // 0..7
    const int lane = tid & 63;
    const int l15  = lane & 15;
    const int lg   = lane >> 4;         // 0..3

    // XCD-bijective swizzle: 512 blocks, 64 contiguous per XCD
    const int bid = (int)blockIdx.x;
    const int swz = (bid & 7) * 64 + (bid >> 3);
    const int rowbase0 = swz * 64;
    const int rowbase1 = swz * 64 + 32;

    // ---- A-phase GEMM (+epilogue to xl); expects x granules in xl ----
    auto stageA_gemm = [&]() {
        f32x4 acc[2][6];
        #pragma unroll
        for (int rt = 0; rt < 2; ++rt)
            #pragma unroll
            for (int jt = 0; jt < 6; ++jt)
                acc[rt][jt] = (f32x4){0.f, 0.f, 0.f, 0.f};

        const int jt0 = w * 6;
        #pragma unroll 2
        for (int et = 0; et < 24; ++et) {
            bf16x8 xfrag[2];
            #pragma unroll
            for (int rt = 0; rt < 2; ++rt)
                xfrag[rt] = *(const bf16x8*)&xl[(((et << 2) + lg) * 32 + rt * 16 + l15) * 8];
            #pragma unroll
            for (int jt = 0; jt < 6; ++jt) {
                const bf16* rp = rot_f + (((size_t)(jt0 + jt) * 24 + et) << 9) + lane * 8;
                bf16x8 rotfrag = *(const bf16x8*)rp;
                acc[0][jt] = __builtin_amdgcn_mfma_f32_16x16x32_bf16(rotfrag, xfrag[0], acc[0][jt], 0, 0, 0);
                acc[1][jt] = __builtin_amdgcn_mfma_f32_16x16x32_bf16(rotfrag, xfrag[1], acc[1][jt], 0, 0, 0);
            }
        }

        lds_barrier();   // all waves done READING x granules

        const int jbase = w * 96;
        #pragma unroll
        for (int rt = 0; rt < 2; ++rt) {
            #pragma unroll
            for (int jt = 0; jt < 6; ++jt) {
                const int j0 = jbase + jt * 16 + lg * 4;
                const int m  = j0 / DSUB;
                const int d0 = j0 % DSUB;
                const int row = rt * 16 + l15;
                bf16x4 v;
                #pragma unroll
                for (int r = 0; r < 4; ++r) v[r] = (bf16)acc[rt][jt][r];
                *(bf16x4*)&xl[(m * 32 + row) * 24 + d0] = v;
            }
        }

        lds_barrier();   // xr visible to all waves
    };

    // ---- Phase B (R16 lean body) for one tile ----
    auto phaseB = [&](int rowbase) {
        const int rt = w >> 2;
        const int kb = (w & 3) * 4;
        const int hi = lg;
        const int srow = rt * 16 + l15;
        const int ssw  = (srow & 7) << 2;

        #pragma unroll 1
        for (int m = 0; m < MSUB; ++m) {
            int off = (m * 32 + srow) * 24 + hi * 8;
            off = off > 24568 ? 24568 : off;
            bf16x8 xfrag = *(const bf16x8*)&xl[off];

            const bf16* cbm = cb_pad + (size_t)m * (KC * 32);
            f32x4 a4[4];
            #pragma unroll
            for (int kk = 0; kk < 4; ++kk) {
                const int kt = kb + kk;
                bf16x8 cfrag = *(const bf16x8*)(cbm + (kt * 16 + l15) * 32 + hi * 8);
                a4[kk] = __builtin_amdgcn_mfma_f32_16x16x32_bf16(
                    cfrag, xfrag, (f32x4){0.f, 0.f, 0.f, 0.f}, 0, 0, 0);
            }

            #pragma unroll
            for (int kk = 0; kk < 4; ++kk) {
                const int kidx = (((kb + kk) * 16 + hi * 4) ^ ssw);
                *(f32x4*)&stg[srow * 256 + kidx] = a4[kk];
            }

            lds_barrier();   // slab complete (stores keep flowing)

            #pragma unroll
            for (int j = 0; j < 4; ++j) {
                const int drow = w * 4 + j;
                const int kidx = (4 * lane) ^ ((drow & 7) << 2);
                f32x4 v = *(const f32x4*)&stg[drow * 256 + kidx];
                *(f32x4*)(out + ((size_t)(rowbase + drow) * MSUB + m) * KC + 4 * lane) = v;
            }

            lds_barrier();   // drain reads done before next stage overwrites
        }
    };

    // ==== Tile 0: A from global ====
    #pragma unroll
    for (int i = 0; i < 6; ++i) {
        const int oct = i * 512 + tid;
        const int row = oct & 31;
        const int e8  = oct >> 5;
        const float* xp = x + (size_t)(rowbase0 + row) * EMB + e8 * 8;
        *(bf16x8*)&xl[(e8 * 32 + row) * 8] =
            cvt8(*(const float4*)xp, *(const float4*)(xp + 4));
    }
    __syncthreads();
    stageA_gemm();

    // ==== Issue x(tile1) prefetch: 12 outstanding float4 loads ====
    float4 pf[12];
    #pragma unroll
    for (int i = 0; i < 6; ++i) {
        const int oct = i * 512 + tid;
        const int row = oct & 31;
        const int e8  = oct >> 5;
        const float* xp = x + (size_t)(rowbase1 + row) * EMB + e8 * 8;
        pf[2 * i]     = *(const float4*)(xp);
        pf[2 * i + 1] = *(const float4*)(xp + 4);
    }

    // ==== B(tile0): ~100us of stores; prefetch completes underneath ====
    phaseB(rowbase0);

    // ==== Tile 1: A from registers (no HBM wait) ====
    #pragma unroll
    for (int i = 0; i < 6; ++i) {
        const int oct = i * 512 + tid;
        const int row = oct & 31;
        const int e8  = oct >> 5;
        *(bf16x8*)&xl[(e8 * 32 + row) * 8] = cvt8(pf[2 * i], pf[2 * i + 1]);
    }
    lds_barrier();
    stageA_gemm();

    // ==== B(tile1) ====
    phaseB(rowbase1);
}

extern "C" void kernel_launch(void* const* d_in, const int* in_sizes, int n_in,
                              void* d_out, int out_size, void* d_ws, size_t ws_size,
                              hipStream_t stream) {
    const float* x   = (const float*)d_in[0];   // [32768, 768]
    const float* cbk = (const float*)d_in[1];   // [32, 256, 24]
    const float* rot = (const float*)d_in[2];   // [768, 768]
    float* out = (float*)d_out;                 // [32768, 32, 256]

    char* ws = (char*)d_ws;
    bf16* cb_pad = (bf16*)(ws);
    bf16* rot_f  = (bf16*)(ws + (1u << 20));

    hipLaunchKernelGGL(pq_prep,   dim3(416), dim3(256), 0, stream, cbk, rot, cb_pad, rot_f);
    hipLaunchKernelGGL(pq_fused5, dim3(512), dim3(512), 0, stream, x, rot_f, cb_pad, out);
}

// Round 22
// 301.401 us; speedup vs baseline: 1.0951x; 1.0951x over previous
//
#include <hip/hip_runtime.h>
#include <hip/hip_bf16.h>

typedef __bf16 bf16;
typedef __bf16 bf16x4 __attribute__((ext_vector_type(4)));
typedef __bf16 bf16x8 __attribute__((ext_vector_type(8)));
typedef float f32x4 __attribute__((ext_vector_type(4)));

#define NB   32768
#define EMB  768
#define MSUB 32
#define KC   256
#define DSUB 24

// ws layout (bytes):
//   [0,     512K )  cb_pad: bf16 [32][256][32]  (d padded 24->32 with zeros)
//   [1M,  2.125M)  rot_f : bf16 fragment-contiguous rotation (see R14)

__device__ __forceinline__ bf16x8 cvt8(float4 a, float4 b) {
    bf16x8 r;
    r[0] = (bf16)a.x; r[1] = (bf16)a.y; r[2] = (bf16)a.z; r[3] = (bf16)a.w;
    r[4] = (bf16)b.x; r[5] = (bf16)b.y; r[6] = (bf16)b.z; r[7] = (bf16)b.w;
    return r;
}

// LDS-only barrier: waits LDS ops (lgkmcnt) but NOT global stores (vmcnt).
__device__ __forceinline__ void lds_barrier() {
    asm volatile("s_waitcnt lgkmcnt(0)" ::: "memory");
    __builtin_amdgcn_s_barrier();
    __builtin_amdgcn_sched_barrier(0);
}

// ---------------------------------------------------------------- kernel 0
__global__ __launch_bounds__(256, 4)
void pq_prep(const float* __restrict__ cb, const float* __restrict__ rot,
             bf16* __restrict__ cb_pad, bf16* __restrict__ rot_f) {
    const int b = blockIdx.x;
    const int t = threadIdx.x;
    if (b < 288) {                       // rot -> fragment-contiguous rot_f
        const int o     = b * 2048 + t * 8;
        const int chunk = o >> 9;              // (jt*24 + et)
        const int lane8 = o & 511;
        const int l15   = (lane8 >> 3) & 15;
        const int lg    = lane8 >> 7;
        const int jj    = (chunk / 24) * 16 + l15;
        const int ee    = (chunk % 24) * 32 + lg * 8;
        const float* rp = rot + (size_t)jj * EMB + ee;
        *(bf16x8*)(rot_f + o) = cvt8(*(const float4*)rp, *(const float4*)(rp + 4));
    } else {                             // cb pad+cvt: [m][k][24] -> bf16 [m][k][32]
        const int o  = (b - 288) * 2048 + t * 8;
        const int m  = o >> 13;
        const int k  = (o >> 5) & 255;
        const int d0 = o & 31;
        bf16x8 v;
        if (d0 < DSUB) {
            const float* cp = cb + (size_t)(m * KC + k) * DSUB + d0;
            v = cvt8(*(const float4*)cp, *(const float4*)(cp + 4));
        } else {
            const float4 fz = {0.f, 0.f, 0.f, 0.f};
            v = cvt8(fz, fz);
        }
        *(bf16x8*)(cb_pad + o) = v;
    }
}

// ---------------------------------------------------------------- kernel 1
// FUSED rot + scores, v6 = R20 (best, 298us) with phase A's et-loop
// manually software-pipelined 2-deep: rot_f L2 loads for et+1 issue while
// et's MFMAs run (compiler left VGPR at 52/128 and did NOT pipeline).
// Two NAMED 6-frag buffers (rotA/rotB) -- no runtime indexing (rule #20).
__global__ __launch_bounds__(512, 4)
void pq_fused6(const float* __restrict__ x, const bf16* __restrict__ rot_f,
               const bf16* __restrict__ cb_pad, float* __restrict__ out) {
    __shared__ __align__(16) char smem[81920];
    bf16*  xl  = (bf16*)smem;                  // 49152 B: x granules, then xr
    float* stg = (float*)(smem + 49152);       // 32768 B: [8 rows][1024] slab

    const int tid  = threadIdx.x;
    const int w    = tid >> 6;          // 0..7
    const int lane = tid & 63;
    const int l15  = lane & 15;
    const int lg   = lane >> 4;         // 0..3

    // XCD-bijective swizzle: 1024 blocks, 128 contiguous per XCD
    const int bid = (int)blockIdx.x;
    const int swz = (bid & 7) * 128 + (bid >> 3);
    const int rowbase = swz * 32;

    // ---- Phase A: stage x -> bf16 granules [e8][row][slot] ----
    #pragma unroll
    for (int i = 0; i < 6; ++i) {
        const int oct = i * 512 + tid;
        const int row = oct & 31;
        const int e8  = oct >> 5;
        const float* xp = x + (size_t)(rowbase + row) * EMB + e8 * 8;
        *(bf16x8*)&xl[(e8 * 32 + row) * 8] =
            cvt8(*(const float4*)xp, *(const float4*)(xp + 4));
    }
    __syncthreads();

    f32x4 acc[2][6];
    #pragma unroll
    for (int rt = 0; rt < 2; ++rt)
        #pragma unroll
        for (int jt = 0; jt < 6; ++jt)
            acc[rt][jt] = (f32x4){0.f, 0.f, 0.f, 0.f};

    const int jt0 = w * 6;
    const bf16* rbase = rot_f + lane * 8;

    // rot fragment address for (jt, et)
    auto raddr = [&](int jt, int et) {
        return rbase + (((size_t)(jt0 + jt) * 24 + et) << 9);
    };

    // 2-deep pipelined et loop: named buffers, static indexing only
    bf16x8 rotA[6], rotB[6];
    #pragma unroll
    for (int jt = 0; jt < 6; ++jt) rotA[jt] = *(const bf16x8*)raddr(jt, 0);

    #pragma unroll 1
    for (int et = 0; et < 24; et += 2) {
        // prefetch et+1 into rotB while MFMA-ing et from rotA
        #pragma unroll
        for (int jt = 0; jt < 6; ++jt) rotB[jt] = *(const bf16x8*)raddr(jt, et + 1);

        bf16x8 xfragA[2];
        #pragma unroll
        for (int rt = 0; rt < 2; ++rt)
            xfragA[rt] = *(const bf16x8*)&xl[(((et << 2) + lg) * 32 + rt * 16 + l15) * 8];
        #pragma unroll
        for (int jt = 0; jt < 6; ++jt) {
            acc[0][jt] = __builtin_amdgcn_mfma_f32_16x16x32_bf16(rotA[jt], xfragA[0], acc[0][jt], 0, 0, 0);
            acc[1][jt] = __builtin_amdgcn_mfma_f32_16x16x32_bf16(rotA[jt], xfragA[1], acc[1][jt], 0, 0, 0);
        }

        // prefetch et+2 into rotA while MFMA-ing et+1 from rotB
        const int e2 = (et + 2 < 24) ? et + 2 : 0;   // uniform clamp, no branch
        #pragma unroll
        for (int jt = 0; jt < 6; ++jt) rotA[jt] = *(const bf16x8*)raddr(jt, e2);

        bf16x8 xfragB[2];
        #pragma unroll
        for (int rt = 0; rt < 2; ++rt)
            xfragB[rt] = *(const bf16x8*)&xl[((((et + 1) << 2) + lg) * 32 + rt * 16 + l15) * 8];
        #pragma unroll
        for (int jt = 0; jt < 6; ++jt) {
            acc[0][jt] = __builtin_amdgcn_mfma_f32_16x16x32_bf16(rotB[jt], xfragB[0], acc[0][jt], 0, 0, 0);
            acc[1][jt] = __builtin_amdgcn_mfma_f32_16x16x32_bf16(rotB[jt], xfragB[1], acc[1][jt], 0, 0, 0);
        }
    }

    lds_barrier();   // all waves done READING x granules

    // epilogue: overwrite xl with xr, layout [(m*32+row)*24 + d]
    const int jbase = w * 96;
    #pragma unroll
    for (int rt = 0; rt < 2; ++rt) {
        #pragma unroll
        for (int jt = 0; jt < 6; ++jt) {
            const int j0 = jbase + jt * 16 + lg * 4;
            const int m  = j0 / DSUB;
            const int d0 = j0 % DSUB;
            const int row = rt * 16 + l15;
            bf16x4 v;
            #pragma unroll
            for (int r = 0; r < 4; ++r) v[r] = (bf16)acc[rt][jt][r];
            *(bf16x4*)&xl[(m * 32 + row) * 24 + d0] = v;
        }
    }

    lds_barrier();   // xr visible to all waves

    // ---- Phase B: 8 m-quads x 4 row-octets, dense 4 KB drains (R20) ----
    const int mi = w >> 1;              // m index within quad 0..3
    const int kh = w & 1;               // k half

    #pragma unroll 1
    for (int mg = 0; mg < 8; ++mg) {
        const int m = mg * 4 + mi;

        // cb fragments for this wave's (m, k-half): read cb ONCE per mg
        const bf16* cbm = cb_pad + (size_t)m * (KC * 32);
        bf16x8 cfrag[8];
        #pragma unroll
        for (int kk = 0; kk < 8; ++kk)
            cfrag[kk] = *(const bf16x8*)(cbm + ((kh * 8 + kk) * 16 + l15) * 32 + lg * 8);

        #pragma unroll 1
        for (int rg = 0; rg < 4; ++rg) {
            // xfrag: row = rg*8 + (l15&7), duplicated in l15 halves;
            // clamp keeps (m=31,row=31,lg=3) overrun inside xl
            int off = (m * 32 + rg * 8 + (l15 & 7)) * 24 + lg * 8;
            off = off > 24568 ? 24568 : off;
            bf16x8 xfrag = *(const bf16x8*)&xl[off];

            f32x4 a8[8];
            #pragma unroll
            for (int kk = 0; kk < 8; ++kk)
                a8[kk] = __builtin_amdgcn_mfma_f32_16x16x32_bf16(
                    cfrag[kk], xfrag, (f32x4){0.f, 0.f, 0.f, 0.f}, 0, 0, 0);

            // stage (first row-copy only): true col = mi*256+kt*16+lg*4,
            // stored at col ^ (row<<2)
            if (l15 < 8) {
                const int row = l15;
                #pragma unroll
                for (int kk = 0; kk < 8; ++kk) {
                    const int col = mi * 256 + (kh * 8 + kk) * 16 + lg * 4;
                    *(f32x4*)&stg[row * 1024 + (col ^ (row << 2))] = a8[kk];
                }
            }

            lds_barrier();   // slab complete (stores keep flowing)

            // drain: wave w -> octet row w; 4 KB contiguous ascending
            {
                const int row = w;
                float* op = out + ((size_t)(rowbase + rg * 8 + row) * MSUB + mg * 4) * KC;
                #pragma unroll
                for (int i = 0; i < 4; ++i) {
                    const int c = i * 256 + 4 * lane;
                    f32x4 v = *(const f32x4*)&stg[row * 1024 + (c ^ (row << 2))];
                    *(f32x4*)(op + c) = v;
                }
            }

            lds_barrier();   // drain reads done before next stage
        }
    }
}

extern "C" void kernel_launch(void* const* d_in, const int* in_sizes, int n_in,
                              void* d_out, int out_size, void* d_ws, size_t ws_size,
                              hipStream_t stream) {
    const float* x   = (const float*)d_in[0];   // [32768, 768]
    const float* cbk = (const float*)d_in[1];   // [32, 256, 24]
    const float* rot = (const float*)d_in[2];   // [768, 768]
    float* out = (float*)d_out;                 // [32768, 32, 256]

    char* ws = (char*)d_ws;
    bf16* cb_pad = (bf16*)(ws);
    bf16* rot_f  = (bf16*)(ws + (1u << 20));

    hipLaunchKernelGGL(pq_prep,   dim3(416),  dim3(256), 0, stream, cbk, rot, cb_pad, rot_f);
    hipLaunchKernelGGL(pq_fused6, dim3(1024), dim3(512), 0, stream, x, rot_f, cb_pad, out);
}

// Round 23
// 242.656 us; speedup vs baseline: 1.3603x; 1.2421x over previous
//
#include <hip/hip_runtime.h>
#include <hip/hip_bf16.h>

typedef __bf16 bf16;
typedef __bf16 bf16x4 __attribute__((ext_vector_type(4)));
typedef __bf16 bf16x8 __attribute__((ext_vector_type(8)));
typedef float f32x4 __attribute__((ext_vector_type(4)));

#define NB   32768
#define EMB  768
#define MSUB 32
#define KC   256
#define DSUB 24

// ws layout (bytes):
//   [0,     512K )  cb_pad: bf16 [32][256][32]  (d padded 24->32 with zeros)
//   [1M,  2.125M)  rot_f : bf16 fragment-contiguous rotation (see R14)

__device__ __forceinline__ bf16x8 cvt8(float4 a, float4 b) {
    bf16x8 r;
    r[0] = (bf16)a.x; r[1] = (bf16)a.y; r[2] = (bf16)a.z; r[3] = (bf16)a.w;
    r[4] = (bf16)b.x; r[5] = (bf16)b.y; r[6] = (bf16)b.z; r[7] = (bf16)b.w;
    return r;
}

// LDS-only barrier: waits LDS ops (lgkmcnt) but NOT global stores (vmcnt).
__device__ __forceinline__ void lds_barrier() {
    asm volatile("s_waitcnt lgkmcnt(0)" ::: "memory");
    __builtin_amdgcn_s_barrier();
    __builtin_amdgcn_sched_barrier(0);
}

// ---------------------------------------------------------------- kernel 0
__global__ __launch_bounds__(256, 4)
void pq_prep(const float* __restrict__ cb, const float* __restrict__ rot,
             bf16* __restrict__ cb_pad, bf16* __restrict__ rot_f) {
    const int b = blockIdx.x;
    const int t = threadIdx.x;
    if (b < 288) {                       // rot -> fragment-contiguous rot_f
        const int o     = b * 2048 + t * 8;
        const int chunk = o >> 9;              // (jt*24 + et)
        const int lane8 = o & 511;
        const int l15   = (lane8 >> 3) & 15;
        const int lg    = lane8 >> 7;
        const int jj    = (chunk / 24) * 16 + l15;
        const int ee    = (chunk % 24) * 32 + lg * 8;
        const float* rp = rot + (size_t)jj * EMB + ee;
        *(bf16x8*)(rot_f + o) = cvt8(*(const float4*)rp, *(const float4*)(rp + 4));
    } else {                             // cb pad+cvt: [m][k][24] -> bf16 [m][k][32]
        const int o  = (b - 288) * 2048 + t * 8;
        const int m  = o >> 13;
        const int k  = (o >> 5) & 255;
        const int d0 = o & 31;
        bf16x8 v;
        if (d0 < DSUB) {
            const float* cp = cb + (size_t)(m * KC + k) * DSUB + d0;
            v = cvt8(*(const float4*)cp, *(const float4*)(cp + 4));
        } else {
            const float4 fz = {0.f, 0.f, 0.f, 0.f};
            v = cvt8(fz, fz);
        }
        *(bf16x8*)(cb_pad + o) = v;
    }
}

// ---------------------------------------------------------------- kernel 1
// FUSED rot + scores, v7 = R20 (best, 298us) with ONE change: drain stores
// are NONTEMPORAL (no L2 write-allocate). The 1 GB out-stream was evicting
// the L2-resident read set (cb_pad + rot_f + x) that A and B re-read --
// suspected cause of fused-B's 5.1 TB/s vs standalone-B's 6.0 TB/s.
__global__ __launch_bounds__(512, 4)
void pq_fused7(const float* __restrict__ x, const bf16* __restrict__ rot_f,
               const bf16* __restrict__ cb_pad, float* __restrict__ out) {
    __shared__ __align__(16) char smem[81920];
    bf16*  xl  = (bf16*)smem;                  // 49152 B: x granules, then xr
    float* stg = (float*)(smem + 49152);       // 32768 B: [8 rows][1024] slab

    const int tid  = threadIdx.x;
    const int w    = tid >> 6;          // 0..7
    const int lane = tid & 63;
    const int l15  = lane & 15;
    const int lg   = lane >> 4;         // 0..3

    // XCD-bijective swizzle: 1024 blocks, 128 contiguous per XCD
    const int bid = (int)blockIdx.x;
    const int swz = (bid & 7) * 128 + (bid >> 3);
    const int rowbase = swz * 32;

    // ---- Phase A: stage x -> bf16 granules [e8][row][slot] ----
    #pragma unroll
    for (int i = 0; i < 6; ++i) {
        const int oct = i * 512 + tid;
        const int row = oct & 31;
        const int e8  = oct >> 5;
        const float* xp = x + (size_t)(rowbase + row) * EMB + e8 * 8;
        *(bf16x8*)&xl[(e8 * 32 + row) * 8] =
            cvt8(*(const float4*)xp, *(const float4*)(xp + 4));
    }
    __syncthreads();

    f32x4 acc[2][6];
    #pragma unroll
    for (int rt = 0; rt < 2; ++rt)
        #pragma unroll
        for (int jt = 0; jt < 6; ++jt)
            acc[rt][jt] = (f32x4){0.f, 0.f, 0.f, 0.f};

    const int jt0 = w * 6;
    #pragma unroll 2
    for (int et = 0; et < 24; ++et) {
        bf16x8 xfrag[2];
        #pragma unroll
        for (int rt = 0; rt < 2; ++rt)
            xfrag[rt] = *(const bf16x8*)&xl[(((et << 2) + lg) * 32 + rt * 16 + l15) * 8];
        #pragma unroll
        for (int jt = 0; jt < 6; ++jt) {
            const bf16* rp = rot_f + (((size_t)(jt0 + jt) * 24 + et) << 9) + lane * 8;
            bf16x8 rotfrag = *(const bf16x8*)rp;
            acc[0][jt] = __builtin_amdgcn_mfma_f32_16x16x32_bf16(rotfrag, xfrag[0], acc[0][jt], 0, 0, 0);
            acc[1][jt] = __builtin_amdgcn_mfma_f32_16x16x32_bf16(rotfrag, xfrag[1], acc[1][jt], 0, 0, 0);
        }
    }

    lds_barrier();   // all waves done READING x granules

    // epilogue: overwrite xl with xr, layout [(m*32+row)*24 + d]
    const int jbase = w * 96;
    #pragma unroll
    for (int rt = 0; rt < 2; ++rt) {
        #pragma unroll
        for (int jt = 0; jt < 6; ++jt) {
            const int j0 = jbase + jt * 16 + lg * 4;
            const int m  = j0 / DSUB;
            const int d0 = j0 % DSUB;
            const int row = rt * 16 + l15;
            bf16x4 v;
            #pragma unroll
            for (int r = 0; r < 4; ++r) v[r] = (bf16)acc[rt][jt][r];
            *(bf16x4*)&xl[(m * 32 + row) * 24 + d0] = v;
        }
    }

    lds_barrier();   // xr visible to all waves

    // ---- Phase B: 8 m-quads x 4 row-octets, dense 4 KB drains ----
    const int mi = w >> 1;              // m index within quad 0..3
    const int kh = w & 1;               // k half

    #pragma unroll 1
    for (int mg = 0; mg < 8; ++mg) {
        const int m = mg * 4 + mi;

        // cb fragments for this wave's (m, k-half): read cb ONCE per mg
        const bf16* cbm = cb_pad + (size_t)m * (KC * 32);
        bf16x8 cfrag[8];
        #pragma unroll
        for (int kk = 0; kk < 8; ++kk)
            cfrag[kk] = *(const bf16x8*)(cbm + ((kh * 8 + kk) * 16 + l15) * 32 + lg * 8);

        #pragma unroll 1
        for (int rg = 0; rg < 4; ++rg) {
            // xfrag: row = rg*8 + (l15&7), duplicated in l15 halves;
            // clamp keeps (m=31,row=31,lg=3) overrun inside xl
            int off = (m * 32 + rg * 8 + (l15 & 7)) * 24 + lg * 8;
            off = off > 24568 ? 24568 : off;
            bf16x8 xfrag = *(const bf16x8*)&xl[off];

            f32x4 a8[8];
            #pragma unroll
            for (int kk = 0; kk < 8; ++kk)
                a8[kk] = __builtin_amdgcn_mfma_f32_16x16x32_bf16(
                    cfrag[kk], xfrag, (f32x4){0.f, 0.f, 0.f, 0.f}, 0, 0, 0);

            // stage (first row-copy only): true col = mi*256+kt*16+lg*4,
            // stored at col ^ (row<<2)
            if (l15 < 8) {
                const int row = l15;
                #pragma unroll
                for (int kk = 0; kk < 8; ++kk) {
                    const int col = mi * 256 + (kh * 8 + kk) * 16 + lg * 4;
                    *(f32x4*)&stg[row * 1024 + (col ^ (row << 2))] = a8[kk];
                }
            }

            lds_barrier();   // slab complete (stores keep flowing)

            // drain: wave w -> octet row w; 4 KB contiguous ascending,
            // NONTEMPORAL (no L2 write-allocate)
            {
                const int row = w;
                float* op = out + ((size_t)(rowbase + rg * 8 + row) * MSUB + mg * 4) * KC;
                #pragma unroll
                for (int i = 0; i < 4; ++i) {
                    const int c = i * 256 + 4 * lane;
                    f32x4 v = *(const f32x4*)&stg[row * 1024 + (c ^ (row << 2))];
                    __builtin_nontemporal_store(v, (f32x4*)(op + c));
                }
            }

            lds_barrier();   // drain reads done before next stage
        }
    }
}

extern "C" void kernel_launch(void* const* d_in, const int* in_sizes, int n_in,
                              void* d_out, int out_size, void* d_ws, size_t ws_size,
                              hipStream_t stream) {
    const float* x   = (const float*)d_in[0];   // [32768, 768]
    const float* cbk = (const float*)d_in[1];   // [32, 256, 24]
    const float* rot = (const float*)d_in[2];   // [768, 768]
    float* out = (float*)d_out;                 // [32768, 32, 256]

    char* ws = (char*)d_ws;
    bf16* cb_pad = (bf16*)(ws);
    bf16* rot_f  = (bf16*)(ws + (1u << 20));

    hipLaunchKernelGGL(pq_prep,   dim3(416),  dim3(256), 0, stream, cbk, rot, cb_pad, rot_f);
    hipLaunchKernelGGL(pq_fused7, dim3(1024), dim3(512), 0, stream, x, rot_f, cb_pad, out);
}

// Round 24
// 242.629 us; speedup vs baseline: 1.3604x; 1.0001x over previous
//
#include <hip/hip_runtime.h>
#include <hip/hip_bf16.h>

typedef __bf16 bf16;
typedef __bf16 bf16x4 __attribute__((ext_vector_type(4)));
typedef __bf16 bf16x8 __attribute__((ext_vector_type(8)));
typedef float f32x4 __attribute__((ext_vector_type(4)));

#define NB   32768
#define EMB  768
#define MSUB 32
#define KC   256
#define DSUB 24

// ws layout (bytes):
//   [0,     512K )  cb_pad: bf16 [32][256][32]  (d padded 24->32 with zeros)
//   [1M,  2.125M)  rot_f : bf16 fragment-contiguous rotation (see R14)

__device__ __forceinline__ bf16x8 cvt8(float4 a, float4 b) {
    bf16x8 r;
    r[0] = (bf16)a.x; r[1] = (bf16)a.y; r[2] = (bf16)a.z; r[3] = (bf16)a.w;
    r[4] = (bf16)b.x; r[5] = (bf16)b.y; r[6] = (bf16)b.z; r[7] = (bf16)b.w;
    return r;
}

// LDS-only barrier: waits LDS ops (lgkmcnt) but NOT global stores (vmcnt).
__device__ __forceinline__ void lds_barrier() {
    asm volatile("s_waitcnt lgkmcnt(0)" ::: "memory");
    __builtin_amdgcn_s_barrier();
    __builtin_amdgcn_sched_barrier(0);
}

// ---------------------------------------------------------------- kernel 0
__global__ __launch_bounds__(256, 4)
void pq_prep(const float* __restrict__ cb, const float* __restrict__ rot,
             bf16* __restrict__ cb_pad, bf16* __restrict__ rot_f) {
    const int b = blockIdx.x;
    const int t = threadIdx.x;
    if (b < 288) {                       // rot -> fragment-contiguous rot_f
        const int o     = b * 2048 + t * 8;
        const int chunk = o >> 9;              // (jt*24 + et)
        const int lane8 = o & 511;
        const int l15   = (lane8 >> 3) & 15;
        const int lg    = lane8 >> 7;
        const int jj    = (chunk / 24) * 16 + l15;
        const int ee    = (chunk % 24) * 32 + lg * 8;
        const float* rp = rot + (size_t)jj * EMB + ee;
        *(bf16x8*)(rot_f + o) = cvt8(*(const float4*)rp, *(const float4*)(rp + 4));
    } else {                             // cb pad+cvt: [m][k][24] -> bf16 [m][k][32]
        const int o  = (b - 288) * 2048 + t * 8;
        const int m  = o >> 13;
        const int k  = (o >> 5) & 255;
        const int d0 = o & 31;
        bf16x8 v;
        if (d0 < DSUB) {
            const float* cp = cb + (size_t)(m * KC + k) * DSUB + d0;
            v = cvt8(*(const float4*)cp, *(const float4*)(cp + 4));
        } else {
            const float4 fz = {0.f, 0.f, 0.f, 0.f};
            v = cvt8(fz, fz);
        }
        *(bf16x8*)(cb_pad + o) = v;
    }
}

// ---------------------------------------------------------------- kernel 1
// FUSED rot + scores, v8 = R23 (best, 242.7us, nt drains) with phase B
// restructured to a DOUBLE-BUFFERED slab: two 16 KB halves ([8 rows][512]
// = 2 m x 256 k), alternating per sub-phase; ONE lgkm-barrier per
// sub-phase and NO post-drain barrier. Hazard chain: drain(p) reads
// half[s] while stage(p+1) writes half[1-s] (disjoint); stage(p+2)
// reuses half[s] only after the next barrier, whose lgkmcnt(0) has
// already retired drain(p)'s LDS reads. Waves flow stores->MFMA->stage
// continuously (no intra-block store-issue gaps).
__global__ __launch_bounds__(512, 4)
void pq_fused8(const float* __restrict__ x, const bf16* __restrict__ rot_f,
               const bf16* __restrict__ cb_pad, float* __restrict__ out) {
    __shared__ __align__(16) char smem[81920];
    bf16*  xl   = (bf16*)smem;                 // 49152 B: x granules, then xr
    float* stg0 = (float*)(smem + 49152);      // 16384 B: half A [8][512]
    float* stg1 = (float*)(smem + 65536);      // 16384 B: half B [8][512]

    const int tid  = threadIdx.x;
    const int w    = tid >> 6;          // 0..7
    const int lane = tid & 63;
    const int l15  = lane & 15;
    const int lg   = lane >> 4;         // 0..3

    // XCD-bijective swizzle: 1024 blocks, 128 contiguous per XCD
    const int bid = (int)blockIdx.x;
    const int swz = (bid & 7) * 128 + (bid >> 3);
    const int rowbase = swz * 32;

    // ---- Phase A: stage x -> bf16 granules [e8][row][slot] ----
    #pragma unroll
    for (int i = 0; i < 6; ++i) {
        const int oct = i * 512 + tid;
        const int row = oct & 31;
        const int e8  = oct >> 5;
        const float* xp = x + (size_t)(rowbase + row) * EMB + e8 * 8;
        *(bf16x8*)&xl[(e8 * 32 + row) * 8] =
            cvt8(*(const float4*)xp, *(const float4*)(xp + 4));
    }
    __syncthreads();

    f32x4 acc[2][6];
    #pragma unroll
    for (int rt = 0; rt < 2; ++rt)
        #pragma unroll
        for (int jt = 0; jt < 6; ++jt)
            acc[rt][jt] = (f32x4){0.f, 0.f, 0.f, 0.f};

    const int jt0 = w * 6;
    #pragma unroll 2
    for (int et = 0; et < 24; ++et) {
        bf16x8 xfrag[2];
        #pragma unroll
        for (int rt = 0; rt < 2; ++rt)
            xfrag[rt] = *(const bf16x8*)&xl[(((et << 2) + lg) * 32 + rt * 16 + l15) * 8];
        #pragma unroll
        for (int jt = 0; jt < 6; ++jt) {
            const bf16* rp = rot_f + (((size_t)(jt0 + jt) * 24 + et) << 9) + lane * 8;
            bf16x8 rotfrag = *(const bf16x8*)rp;
            acc[0][jt] = __builtin_amdgcn_mfma_f32_16x16x32_bf16(rotfrag, xfrag[0], acc[0][jt], 0, 0, 0);
            acc[1][jt] = __builtin_amdgcn_mfma_f32_16x16x32_bf16(rotfrag, xfrag[1], acc[1][jt], 0, 0, 0);
        }
    }

    lds_barrier();   // all waves done READING x granules

    // epilogue: overwrite xl with xr, layout [(m*32+row)*24 + d]
    const int jbase = w * 96;
    #pragma unroll
    for (int rt = 0; rt < 2; ++rt) {
        #pragma unroll
        for (int jt = 0; jt < 6; ++jt) {
            const int j0 = jbase + jt * 16 + lg * 4;
            const int m  = j0 / DSUB;
            const int d0 = j0 % DSUB;
            const int row = rt * 16 + l15;
            bf16x4 v;
            #pragma unroll
            for (int r = 0; r < 4; ++r) v[r] = (bf16)acc[rt][jt][r];
            *(bf16x4*)&xl[(m * 32 + row) * 24 + d0] = v;
        }
    }

    lds_barrier();   // xr visible to all waves

    // ---- Phase B: 16 m-pairs x 4 row-octets, double-buffered slab ----
    const int mi = w >> 2;              // m index within pair: 0..1
    const int kh = w & 3;               // k quarter: 0..3

    #pragma unroll 1
    for (int mp = 0; mp < 16; ++mp) {
        const int m = mp * 2 + mi;

        // cb fragments for this wave's (m, k-quarter): 4 tiles
        const bf16* cbm = cb_pad + (size_t)m * (KC * 32);
        bf16x8 cfrag[4];
        #pragma unroll
        for (int kk = 0; kk < 4; ++kk)
            cfrag[kk] = *(const bf16x8*)(cbm + ((kh * 4 + kk) * 16 + l15) * 32 + lg * 8);

        #pragma unroll 1
        for (int rg = 0; rg < 4; ++rg) {
            float* s = ((mp * 4 + rg) & 1) ? stg1 : stg0;

            // xfrag: row = rg*8 + (l15&7), duplicated in l15 halves;
            // clamp keeps (m=31,row=31,lg=3) overrun inside xl
            int off = (m * 32 + rg * 8 + (l15 & 7)) * 24 + lg * 8;
            off = off > 24568 ? 24568 : off;
            bf16x8 xfrag = *(const bf16x8*)&xl[off];

            f32x4 a4[4];
            #pragma unroll
            for (int kk = 0; kk < 4; ++kk)
                a4[kk] = __builtin_amdgcn_mfma_f32_16x16x32_bf16(
                    cfrag[kk], xfrag, (f32x4){0.f, 0.f, 0.f, 0.f}, 0, 0, 0);

            // stage (first row-copy only): true col = mi*256+kt*16+lg*4,
            // stored at col ^ (row<<2) within [8][512] half-slab
            if (l15 < 8) {
                const int row = l15;
                #pragma unroll
                for (int kk = 0; kk < 4; ++kk) {
                    const int col = mi * 256 + (kh * 4 + kk) * 16 + lg * 4;
                    *(f32x4*)&s[row * 512 + (col ^ (row << 2))] = a4[kk];
                }
            }

            lds_barrier();   // stage visible; stores keep flowing; NO 2nd bar

            // drain: wave w -> octet row w; 2 KB contiguous (2 consecutive
            // m), nontemporal full 1 KB lines
            {
                const int row = w;
                float* op = out + ((size_t)(rowbase + rg * 8 + row) * MSUB + mp * 2) * KC;
                #pragma unroll
                for (int i = 0; i < 2; ++i) {
                    const int c = i * 256 + 4 * lane;
                    f32x4 v = *(const f32x4*)&s[row * 512 + (c ^ (row << 2))];
                    __builtin_nontemporal_store(v, (f32x4*)(op + c));
                }
            }
            // next stage targets the OTHER half-slab: no barrier needed here
        }
    }
}

extern "C" void kernel_launch(void* const* d_in, const int* in_sizes, int n_in,
                              void* d_out, int out_size, void* d_ws, size_t ws_size,
                              hipStream_t stream) {
    const float* x   = (const float*)d_in[0];   // [32768, 768]
    const float* cbk = (const float*)d_in[1];   // [32, 256, 24]
    const float* rot = (const float*)d_in[2];   // [768, 768]
    float* out = (float*)d_out;                 // [32768, 32, 256]

    char* ws = (char*)d_ws;
    bf16* cb_pad = (bf16*)(ws);
    bf16* rot_f  = (bf16*)(ws + (1u << 20));

    hipLaunchKernelGGL(pq_prep,   dim3(416),  dim3(256), 0, stream, cbk, rot, cb_pad, rot_f);
    hipLaunchKernelGGL(pq_fused8, dim3(1024), dim3(512), 0, stream, x, rot_f, cb_pad, out);
}